// Round 2
// baseline (970.354 us; speedup 1.0000x reference)
//
#include <hip/hip_runtime.h>
#include <math.h>

#define NN 100000
#define NE 3200000

constexpr int BLK = 256;
constexpr int GRID_EDGE = 2048;
constexpr int NBUCKET = 64;

// ws layout (floats):
//   [0 : 64*32)        stats buckets (memset 0 each launch)
//   [2048 : 2080)      scale[16], shift[16]
//   [4096 : ...)       p1 (NN*16), then p2 (NN*16)

__device__ __forceinline__ void load_row16(const float* __restrict__ base,
                                           size_t row, float v[16]) {
  const float4* r = (const float4*)(base + row * 16);
#pragma unroll
  for (int qq = 0; qq < 4; ++qq) {
    float4 t = r[qq];
    v[qq * 4 + 0] = t.x; v[qq * 4 + 1] = t.y;
    v[qq * 4 + 2] = t.z; v[qq * 4 + 3] = t.w;
  }
}

__device__ __forceinline__ void matvec16_acc(const float* __restrict__ sW,
                                             const float v[16], float acc[16]) {
#pragma unroll
  for (int j = 0; j < 16; ++j) {
    float a = acc[j];
#pragma unroll
    for (int qq = 0; qq < 4; ++qq) {
      float4 w = ((const float4*)(sW + j * 16))[qq];
      a = fmaf(v[qq * 4 + 0], w.x, a);
      a = fmaf(v[qq * 4 + 1], w.y, a);
      a = fmaf(v[qq * 4 + 2], w.z, a);
      a = fmaf(v[qq * 4 + 3], w.w, a);
    }
    acc[j] = a;
  }
}

__global__ __launch_bounds__(BLK)
void node_proj(const float* __restrict__ x, const float* __restrict__ W1,
               const float* __restrict__ W2, float* __restrict__ p1,
               float* __restrict__ p2) {
  __shared__ __align__(16) float sW1[256];
  __shared__ __align__(16) float sW2[256];
  for (int i = threadIdx.x; i < 256; i += BLK) { sW1[i] = W1[i]; sW2[i] = W2[i]; }
  __syncthreads();
  int n = blockIdx.x * BLK + threadIdx.x;
  if (n >= NN) return;
  float xv[16];
  load_row16(x, (size_t)n, xv);
  float y1[16], y2[16];
#pragma unroll
  for (int j = 0; j < 16; ++j) { y1[j] = 0.f; y2[j] = 0.f; }
  matvec16_acc(sW1, xv, y1);
  matvec16_acc(sW2, xv, y2);
  float4* o1 = (float4*)(p1 + (size_t)n * 16);
  float4* o2 = (float4*)(p2 + (size_t)n * 16);
#pragma unroll
  for (int qq = 0; qq < 4; ++qq) {
    o1[qq] = make_float4(y1[qq*4+0], y1[qq*4+1], y1[qq*4+2], y1[qq*4+3]);
    o2[qq] = make_float4(y2[qq*4+0], y2[qq*4+1], y2[qq*4+2], y2[qq*4+3]);
  }
}

// 4 lanes per edge; lane q = tid&3 owns output channels 4q..4q+3.
// PASS2==false: accumulate per-channel sum/sumsq into stats buckets.
// PASS2==true : recompute e, scale/shift + relu + residual, write out.
template <bool PASS2>
__global__ __launch_bounds__(BLK, 6)
void edge_kernel(const float* __restrict__ ea, const int* __restrict__ ei,
                 const float* __restrict__ p1, const float* __restrict__ p2,
                 const float* __restrict__ W0g,
                 float* __restrict__ stats, const float* __restrict__ ssg,
                 float* __restrict__ out) {
  __shared__ __align__(16) float sW0T[256];  // sW0T[k*16+j] = W0[j*16+k]
  __shared__ float sSS[32];
  __shared__ float red[4][32];
  for (int i = threadIdx.x; i < 256; i += BLK) {
    int j = i & 15, k = i >> 4;
    sW0T[i] = W0g[j * 16 + k];
  }
  if (PASS2 && threadIdx.x < 32) sSS[threadIdx.x] = ssg[threadIdx.x];
  __syncthreads();

  const int q = threadIdx.x & 3;
  float sum0 = 0.f, sum1 = 0.f, sum2 = 0.f, sum3 = 0.f;
  float ssq0 = 0.f, ssq1 = 0.f, ssq2 = 0.f, ssq3 = 0.f;

  float sc0, sc1, sc2, sc3, sh0, sh1, sh2, sh3;
  if (PASS2) {
    sc0 = sSS[q*4+0]; sc1 = sSS[q*4+1]; sc2 = sSS[q*4+2]; sc3 = sSS[q*4+3];
    sh0 = sSS[16+q*4+0]; sh1 = sSS[16+q*4+1]; sh2 = sSS[16+q*4+2]; sh3 = sSS[16+q*4+3];
  }

  const int estride = (gridDim.x * BLK) >> 2;
  for (int e = (blockIdx.x * BLK + threadIdx.x) >> 2; e < NE; e += estride) {
    int s = ei[e];
    int d = ei[NE + e];
    float4 ps = *(const float4*)(p1 + (size_t)s * 16 + q * 4);
    float4 pd = *(const float4*)(p2 + (size_t)d * 16 + q * 4);
    float eav[16];
    load_row16(ea, (size_t)e, eav);
    float a0 = ps.x + pd.x, a1 = ps.y + pd.y, a2 = ps.z + pd.z, a3 = ps.w + pd.w;
#pragma unroll
    for (int k = 0; k < 16; ++k) {
      float4 w = *(const float4*)(sW0T + k * 16 + q * 4);
      a0 = fmaf(eav[k], w.x, a0);
      a1 = fmaf(eav[k], w.y, a1);
      a2 = fmaf(eav[k], w.z, a2);
      a3 = fmaf(eav[k], w.w, a3);
    }
    if (!PASS2) {
      sum0 += a0; sum1 += a1; sum2 += a2; sum3 += a3;
      ssq0 = fmaf(a0, a0, ssq0); ssq1 = fmaf(a1, a1, ssq1);
      ssq2 = fmaf(a2, a2, ssq2); ssq3 = fmaf(a3, a3, ssq3);
    } else {
      float4 res = *(const float4*)(ea + (size_t)e * 16 + q * 4);
      float4 o;
      o.x = res.x + fmaxf(0.f, fmaf(a0, sc0, sh0));
      o.y = res.y + fmaxf(0.f, fmaf(a1, sc1, sh1));
      o.z = res.z + fmaxf(0.f, fmaf(a2, sc2, sh2));
      o.w = res.w + fmaxf(0.f, fmaf(a3, sc3, sh3));
      *(float4*)(out + (size_t)e * 16 + q * 4) = o;
    }
  }

  if (!PASS2) {
    // reduce across the 16 lanes sharing each q (lane&3 invariant under these xors)
#pragma unroll
    for (int off = 4; off <= 32; off <<= 1) {
      sum0 += __shfl_xor(sum0, off); sum1 += __shfl_xor(sum1, off);
      sum2 += __shfl_xor(sum2, off); sum3 += __shfl_xor(sum3, off);
      ssq0 += __shfl_xor(ssq0, off); ssq1 += __shfl_xor(ssq1, off);
      ssq2 += __shfl_xor(ssq2, off); ssq3 += __shfl_xor(ssq3, off);
    }
    int wid = threadIdx.x >> 6;
    int lane = threadIdx.x & 63;
    if (lane < 4) {
      red[wid][lane * 4 + 0] = sum0; red[wid][lane * 4 + 1] = sum1;
      red[wid][lane * 4 + 2] = sum2; red[wid][lane * 4 + 3] = sum3;
      red[wid][16 + lane * 4 + 0] = ssq0; red[wid][16 + lane * 4 + 1] = ssq1;
      red[wid][16 + lane * 4 + 2] = ssq2; red[wid][16 + lane * 4 + 3] = ssq3;
    }
    __syncthreads();
    if (threadIdx.x < 32) {
      float v = red[0][threadIdx.x] + red[1][threadIdx.x] +
                red[2][threadIdx.x] + red[3][threadIdx.x];
      atomicAdd(stats + (blockIdx.x & (NBUCKET - 1)) * 32 + threadIdx.x, v);
    }
  }
}

__global__ void finalize_kernel(const float* __restrict__ stats,
                                const float* __restrict__ gamma,
                                const float* __restrict__ beta,
                                float* __restrict__ ss) {
  __shared__ float tot[32];
  int t = threadIdx.x;
  if (t < 32) {
    float v = 0.f;
    for (int b = 0; b < NBUCKET; ++b) v += stats[b * 32 + t];
    tot[t] = v;
  }
  __syncthreads();
  if (t < 16) {
    const float inv_n = 1.0f / (float)NE;
    float mean = tot[t] * inv_n;
    float var = fmaf(-mean, mean, tot[16 + t] * inv_n);
    float sc = gamma[t] / sqrtf(var + 1e-5f);
    ss[t] = sc;
    ss[16 + t] = fmaf(-mean, sc, beta[t]);
  }
}

// ---- fallback path (no workspace for p1/p2): per-lane full-row gathers ----
template <bool PASS2>
__global__ __launch_bounds__(BLK, 4)
void edge_kernel_nopre(const float* __restrict__ ea, const int* __restrict__ ei,
                       const float* __restrict__ x,
                       const float* __restrict__ W0g, const float* __restrict__ W1g,
                       const float* __restrict__ W2g,
                       float* __restrict__ stats, const float* __restrict__ ssg,
                       float* __restrict__ out) {
  __shared__ __align__(16) float sW0T[256], sW1T[256], sW2T[256];
  __shared__ float sSS[32];
  __shared__ float red[4][32];
  for (int i = threadIdx.x; i < 256; i += BLK) {
    int j = i & 15, k = i >> 4;
    sW0T[i] = W0g[j * 16 + k];
    sW1T[i] = W1g[j * 16 + k];
    sW2T[i] = W2g[j * 16 + k];
  }
  if (PASS2 && threadIdx.x < 32) sSS[threadIdx.x] = ssg[threadIdx.x];
  __syncthreads();

  const int q = threadIdx.x & 3;
  float sum[4] = {0,0,0,0}, ssq[4] = {0,0,0,0};

  const int estride = (gridDim.x * BLK) >> 2;
  for (int e = (blockIdx.x * BLK + threadIdx.x) >> 2; e < NE; e += estride) {
    int s = ei[e];
    int d = ei[NE + e];
    float eav[16], xs[16], xd[16];
    load_row16(ea, (size_t)e, eav);
    load_row16(x, (size_t)s, xs);
    load_row16(x, (size_t)d, xd);
    float a[4] = {0.f, 0.f, 0.f, 0.f};
#pragma unroll
    for (int k = 0; k < 16; ++k) {
      float4 w0 = *(const float4*)(sW0T + k * 16 + q * 4);
      float4 w1 = *(const float4*)(sW1T + k * 16 + q * 4);
      float4 w2 = *(const float4*)(sW2T + k * 16 + q * 4);
      a[0] = fmaf(eav[k], w0.x, fmaf(xs[k], w1.x, fmaf(xd[k], w2.x, a[0])));
      a[1] = fmaf(eav[k], w0.y, fmaf(xs[k], w1.y, fmaf(xd[k], w2.y, a[1])));
      a[2] = fmaf(eav[k], w0.z, fmaf(xs[k], w1.z, fmaf(xd[k], w2.z, a[2])));
      a[3] = fmaf(eav[k], w0.w, fmaf(xs[k], w1.w, fmaf(xd[k], w2.w, a[3])));
    }
    if (!PASS2) {
#pragma unroll
      for (int jj = 0; jj < 4; ++jj) {
        sum[jj] += a[jj];
        ssq[jj] = fmaf(a[jj], a[jj], ssq[jj]);
      }
    } else {
      float4 res = *(const float4*)(ea + (size_t)e * 16 + q * 4);
      float4 o;
      o.x = res.x + fmaxf(0.f, fmaf(a[0], sSS[q*4+0], sSS[16+q*4+0]));
      o.y = res.y + fmaxf(0.f, fmaf(a[1], sSS[q*4+1], sSS[16+q*4+1]));
      o.z = res.z + fmaxf(0.f, fmaf(a[2], sSS[q*4+2], sSS[16+q*4+2]));
      o.w = res.w + fmaxf(0.f, fmaf(a[3], sSS[q*4+3], sSS[16+q*4+3]));
      *(float4*)(out + (size_t)e * 16 + q * 4) = o;
    }
  }

  if (!PASS2) {
#pragma unroll
    for (int off = 4; off <= 32; off <<= 1) {
#pragma unroll
      for (int jj = 0; jj < 4; ++jj) {
        sum[jj] += __shfl_xor(sum[jj], off);
        ssq[jj] += __shfl_xor(ssq[jj], off);
      }
    }
    int wid = threadIdx.x >> 6;
    int lane = threadIdx.x & 63;
    if (lane < 4) {
#pragma unroll
      for (int jj = 0; jj < 4; ++jj) {
        red[wid][lane * 4 + jj] = sum[jj];
        red[wid][16 + lane * 4 + jj] = ssq[jj];
      }
    }
    __syncthreads();
    if (threadIdx.x < 32) {
      float v = red[0][threadIdx.x] + red[1][threadIdx.x] +
                red[2][threadIdx.x] + red[3][threadIdx.x];
      atomicAdd(stats + (blockIdx.x & (NBUCKET - 1)) * 32 + threadIdx.x, v);
    }
  }
}

extern "C" void kernel_launch(void* const* d_in, const int* in_sizes, int n_in,
                              void* d_out, int out_size, void* d_ws, size_t ws_size,
                              hipStream_t stream) {
  const float* x     = (const float*)d_in[0];
  const int*   ei    = (const int*)d_in[1];
  const float* ea    = (const float*)d_in[2];
  const float* W0    = (const float*)d_in[3];
  const float* W1    = (const float*)d_in[5];
  const float* W2    = (const float*)d_in[7];
  const float* gamma = (const float*)d_in[9];
  const float* beta  = (const float*)d_in[10];
  float* out = (float*)d_out;

  float* ws    = (float*)d_ws;
  float* stats = ws;          // 64*32 floats
  float* ss    = ws + 2048;   // 32 floats
  float* p1    = ws + 4096;
  float* p2    = p1 + (size_t)NN * 16;
  size_t need = (4096 + 2 * (size_t)NN * 16) * sizeof(float);
  bool use_pre = ws_size >= need;

  hipMemsetAsync(stats, 0, NBUCKET * 32 * sizeof(float), stream);

  if (use_pre) {
    node_proj<<<(NN + BLK - 1) / BLK, BLK, 0, stream>>>(x, W1, W2, p1, p2);
    edge_kernel<false><<<GRID_EDGE, BLK, 0, stream>>>(
        ea, ei, p1, p2, W0, stats, nullptr, out);
    finalize_kernel<<<1, 64, 0, stream>>>(stats, gamma, beta, ss);
    edge_kernel<true><<<GRID_EDGE, BLK, 0, stream>>>(
        ea, ei, p1, p2, W0, stats, ss, out);
  } else {
    edge_kernel_nopre<false><<<GRID_EDGE, BLK, 0, stream>>>(
        ea, ei, x, W0, W1, W2, stats, nullptr, out);
    finalize_kernel<<<1, 64, 0, stream>>>(stats, gamma, beta, ss);
    edge_kernel_nopre<true><<<GRID_EDGE, BLK, 0, stream>>>(
        ea, ei, x, W0, W1, W2, stats, ss, out);
  }
}